// Round 19
// baseline (691.339 us; speedup 1.0000x reference)
//
#include <hip/hip_runtime.h>

// Problem constants
#define NN 16384
// ws (bf16) region offsets, in elements
#define OFF_EWT 0
#define OFF_WQT 4096
#define OFF_WKT 36864
#define OFF_WVT 69632
#define OFF_AFT 102400
#define OFF_W1T 135168
#define OFF_W2T 266240
#define OFF_F2N 397312
#define TOTAL_W 413696
#define FB_BYTE_OFF (1 << 20)   // fbuf starts 1MB into d_ws; 16384 nodes x 4KB = 64MB

typedef __attribute__((ext_vector_type(8))) short bf16x8;
typedef __attribute__((ext_vector_type(4))) short bf16x4;
typedef __attribute__((ext_vector_type(4))) float f32x4;

static __device__ __forceinline__ short f2bf(float f) {
  unsigned u = __builtin_bit_cast(unsigned, f);
  u += 0x7fffu + ((u >> 16) & 1u);           // RNE
  return (short)(u >> 16);
}
static __device__ __forceinline__ float bf2f(short h) {
  unsigned u = ((unsigned)(unsigned short)h) << 16;
  return __builtin_bit_cast(float, u);
}
static __device__ __forceinline__ float gelu_f(float x) {
  float e = __expf(1.5957691216057308f * (x + 0.044715f * x * x * x));
  return x - x / (e + 1.0f);
}
static __device__ __forceinline__ f32x4 mfma16(bf16x8 a, bf16x8 b, f32x4 c) {
  return __builtin_amdgcn_mfma_f32_16x16x32_bf16(a, b, c, 0, 0, 0);
}
// XOR bank swizzle
#define SWZM(row) (((((row) & 7) << 4)) ^ ((((row) >> 3) & 3) << 5))
static __device__ __forceinline__ int swzb(int row, int col) {
  return row * 256 + ((col * 2) ^ SWZM(row));
}
static __device__ __forceinline__ bf16x8 tile_ld8(const short* base, int row, int col) {
  return *(const bf16x8*)((const char*)base + swzb(row, col));
}
static __device__ __forceinline__ void tile_st16(short* base, int row, int col, short v) {
  *(short*)((char*)base + swzb(row, col)) = v;
}
static __device__ __forceinline__ float tile_ldf(const short* base, int row, int col) {
  return bf2f(*(const short*)((const char*)base + swzb(row, col)));
}
static __device__ __forceinline__ void gll16(const short* sp, void* dstb) {
  __builtin_amdgcn_global_load_lds(
      (const __attribute__((address_space(1))) unsigned int*)sp,
      (__attribute__((address_space(3))) unsigned int*)dstb, 16, 0, 0);
}
// 16KB half stage for 8-wave WGs: 2 gll16 per wave (64 rows x 128)
static __device__ __forceinline__ void stage_h8(short* dst, const short* src, int stride,
                                                int w, int lane) {
  #pragma unroll
  for (int it = 0; it < 2; ++it) {
    int dbase = (it * 8 + w) * 1024;
    int d = dbase + lane * 16;
    int row = d >> 8;                        // 0..63
    int scolb = (d & 255) ^ SWZM(row);
    gll16(src + row * stride + (scolb >> 1), (char*)dst + dbase);
  }
}
// 16KB half stage for 4-wave WGs (ffn): 4 gll16 per wave (64 rows x 128)
static __device__ __forceinline__ void stage_h4(short* dst, const short* src, int stride,
                                                int w, int lane) {
  #pragma unroll
  for (int it = 0; it < 4; ++it) {
    int dbase = (it * 4 + w) * 1024;
    int d = dbase + lane * 16;
    int row = d >> 8;                        // 0..63
    int scolb = (d & 255) ^ SWZM(row);
    gll16(src + row * stride + (scolb >> 1), (char*)dst + dbase);
  }
}
// 4KB f-tile stage (16 rows x 128), per wave into its own tile
static __device__ __forceinline__ void stage_f(short* dst, const short* src, int lane) {
  #pragma unroll
  for (int it = 0; it < 4; ++it) {
    int dbase = it * 1024;
    int d = dbase + lane * 16;
    int row = d >> 8;                        // 0..15
    int scolb = (d & 255) ^ SWZM(row);
    gll16(src + row * 128 + (scolb >> 1), (char*)dst + dbase);
  }
}

#define LDS_FENCE() do {                                       \
    asm volatile("s_waitcnt lgkmcnt(0)" ::: "memory");         \
    __builtin_amdgcn_sched_barrier(0);                         \
  } while (0)

#define ENDSTEP() do {                                         \
    __syncthreads();                                           \
    short* _t = bc; bc = bn; bn = _t;                          \
  } while (0)

#define LD_FA(SRC)                                                        \
  _Pragma("unroll") for (int _s = 0; _s < 4; ++_s)                        \
      fA[_s] = tile_ld8((SRC), li, _s * 32 + lq * 8);

#define ST_TILE(T, ACC)                                                   \
  _Pragma("unroll") for (int _c = 0; _c < 8; ++_c)                        \
    _Pragma("unroll") for (int _r = 0; _r < 4; ++_r)                      \
      tile_st16((T), lq * 4 + _r, _c * 16 + li, f2bf((ACC)[_c][_r]));

// 64-row half projection with row offset: 16 B-frag reads feed 16 MFMAs
#define PROJ4H(BB, RO)                                                    \
    f32x4 g0 = F0, g1 = F0, g2 = F0, g3 = F0;                             \
    _Pragma("unroll") for (int _s = 0; _s < 4; ++_s) {                    \
      int _sc = _s * 32 + lq * 8;                                         \
      g0 = mfma16(fA[_s], tile_ld8((BB), (RO) + 0 + li, _sc), g0);        \
      g1 = mfma16(fA[_s], tile_ld8((BB), (RO) + 16 + li, _sc), g1);       \
      g2 = mfma16(fA[_s], tile_ld8((BB), (RO) + 32 + li, _sc), g2);       \
      g3 = mfma16(fA[_s], tile_ld8((BB), (RO) + 48 + li, _sc), g3);       \
    }

// store the 4 half-projection tiles into DST at col-block base HB*4
#define ST4H(DST, HB)                                                     \
    _Pragma("unroll") for (int _r = 0; _r < 4; ++_r) {                    \
      tile_st16((DST), lq * 4 + _r, ((HB) * 4 + 0) * 16 + li, f2bf(g0[_r])); \
      tile_st16((DST), lq * 4 + _r, ((HB) * 4 + 1) * 16 + li, f2bf(g1[_r])); \
      tile_st16((DST), lq * 4 + _r, ((HB) * 4 + 2) * 16 + li, f2bf(g2[_r])); \
      tile_st16((DST), lq * 4 + _r, ((HB) * 4 + 3) * 16 + li, f2bf(g3[_r])); \
    }

// half accumulate with row offset: acc[CB..CB+3] += A * staged rows RO..RO+63
#define ACC4H(AR, CB, BB, RO)                                             \
    _Pragma("unroll") for (int _s = 0; _s < 4; ++_s) {                    \
      int _sc = _s * 32 + lq * 8;                                         \
      acc[(CB) + 0] = mfma16(AR[_s], tile_ld8((BB), (RO) + 0 + li, _sc), acc[(CB) + 0]);  \
      acc[(CB) + 1] = mfma16(AR[_s], tile_ld8((BB), (RO) + 16 + li, _sc), acc[(CB) + 1]); \
      acc[(CB) + 2] = mfma16(AR[_s], tile_ld8((BB), (RO) + 32 + li, _sc), acc[(CB) + 2]); \
      acc[(CB) + 3] = mfma16(AR[_s], tile_ld8((BB), (RO) + 48 + li, _sc), acc[(CB) + 3]); \
    }

// dual-node half projection: 16 B-frag reads feed 32 MFMAs
#define PROJ2H(BB)                                                        \
    f32x4 ga0 = F0, ga1 = F0, ga2 = F0, ga3 = F0;                         \
    f32x4 gb0 = F0, gb1 = F0, gb2 = F0, gb3 = F0;                         \
    _Pragma("unroll") for (int _s = 0; _s < 4; ++_s) {                    \
      int _sc = _s * 32 + lq * 8;                                         \
      bf16x8 _b0 = tile_ld8((BB), 0 + li, _sc);                           \
      bf16x8 _b1 = tile_ld8((BB), 16 + li, _sc);                          \
      bf16x8 _b2 = tile_ld8((BB), 32 + li, _sc);                          \
      bf16x8 _b3 = tile_ld8((BB), 48 + li, _sc);                          \
      ga0 = mfma16(fA0[_s], _b0, ga0); gb0 = mfma16(fA1[_s], _b0, gb0);   \
      ga1 = mfma16(fA0[_s], _b1, ga1); gb1 = mfma16(fA1[_s], _b1, gb1);   \
      ga2 = mfma16(fA0[_s], _b2, ga2); gb2 = mfma16(fA1[_s], _b2, gb2);   \
      ga3 = mfma16(fA0[_s], _b3, ga3); gb3 = mfma16(fA1[_s], _b3, gb3);   \
    }

// dual-node half accumulate: acc{0,1}[CB..CB+3] += A{0,1} * staged half
#define ACC2H(AR0, AR1, CB, BB)                                           \
    _Pragma("unroll") for (int _s = 0; _s < 4; ++_s) {                    \
      int _sc = _s * 32 + lq * 8;                                         \
      bf16x8 _b0 = tile_ld8((BB), 0 + li, _sc);                           \
      bf16x8 _b1 = tile_ld8((BB), 16 + li, _sc);                          \
      bf16x8 _b2 = tile_ld8((BB), 32 + li, _sc);                          \
      bf16x8 _b3 = tile_ld8((BB), 48 + li, _sc);                          \
      acc0[(CB) + 0] = mfma16(AR0[_s], _b0, acc0[(CB) + 0]);              \
      acc1[(CB) + 0] = mfma16(AR1[_s], _b0, acc1[(CB) + 0]);              \
      acc0[(CB) + 1] = mfma16(AR0[_s], _b1, acc0[(CB) + 1]);              \
      acc1[(CB) + 1] = mfma16(AR1[_s], _b1, acc1[(CB) + 1]);              \
      acc0[(CB) + 2] = mfma16(AR0[_s], _b2, acc0[(CB) + 2]);              \
      acc1[(CB) + 2] = mfma16(AR1[_s], _b2, acc1[(CB) + 2]);              \
      acc0[(CB) + 3] = mfma16(AR0[_s], _b3, acc0[(CB) + 3]);              \
      acc1[(CB) + 3] = mfma16(AR1[_s], _b3, acc1[(CB) + 3]);              \
    }

#define LAYER_NORM(A, GP, BP) do {                                        \
    float _gg[8], _bb[8];                                                 \
    _Pragma("unroll") for (int _c = 0; _c < 8; ++_c) {                    \
      _gg[_c] = (GP)[_c * 16 + li]; _bb[_c] = (BP)[_c * 16 + li]; }       \
    _Pragma("unroll") for (int _r = 0; _r < 4; ++_r) {                    \
      float _s1 = 0.f, _s2 = 0.f;                                         \
      _Pragma("unroll") for (int _c = 0; _c < 8; ++_c) {                  \
        float _v = (A)[_c][_r]; _s1 += _v; _s2 += _v * _v; }              \
      _Pragma("unroll") for (int _m = 1; _m <= 8; _m <<= 1) {             \
        _s1 += __shfl_xor(_s1, _m, 64); _s2 += __shfl_xor(_s2, _m, 64); } \
      float _mean = _s1 * (1.f / 128.f);                                  \
      float _var = _s2 * (1.f / 128.f) - _mean * _mean;                   \
      float _rstd = rsqrtf(_var + 1e-5f);                                 \
      _Pragma("unroll") for (int _c = 0; _c < 8; ++_c)                    \
        (A)[_c][_r] = ((A)[_c][_r] - _mean) * _rstd * _gg[_c] + _bb[_c];  \
    }                                                                     \
  } while (0)

// wave-private attention; overlays Vt->MYK, Os->MYQ (both dead)
#define ATTN(MYQ, MYK, VACC, OA) do {                                     \
    f32x4 _st[8];                                                         \
    _Pragma("unroll") for (int _h = 0; _h < 8; ++_h) {                    \
      bf16x8 _ka = B0, _qa = B0;                                          \
      if (lq < 2) {                                                       \
        _ka = tile_ld8((MYK), li, _h * 16 + lq * 8);                      \
        _qa = tile_ld8((MYQ), li, _h * 16 + lq * 8);                      \
      }                                                                   \
      _st[_h] = mfma16(_ka, _qa, F0);                                     \
    }                                                                     \
    LDS_FENCE();                                                          \
    _Pragma("unroll") for (int _c = 0; _c < 8; ++_c) {                    \
      bf16x4 _pk;                                                         \
      _Pragma("unroll") for (int _r = 0; _r < 4; ++_r)                    \
        _pk[_r] = f2bf((VACC)[_c][_r]);                                   \
      *(bf16x4*)((MYK) + (_c * 16 + li) * 16 + lq * 4) = _pk;             \
    }                                                                     \
    LDS_FENCE();                                                          \
    _Pragma("unroll") for (int _h = 0; _h < 8; ++_h) {                    \
      float _p[4]; float _mx = -1e30f;                                    \
      _Pragma("unroll") for (int _r = 0; _r < 4; ++_r) {                  \
        _p[_r] = _st[_h][_r] * 0.25f; _mx = fmaxf(_mx, _p[_r]); }         \
      _mx = fmaxf(_mx, __shfl_xor(_mx, 16, 64));                          \
      _mx = fmaxf(_mx, __shfl_xor(_mx, 32, 64));                          \
      float _sum = 0.f;                                                   \
      _Pragma("unroll") for (int _r = 0; _r < 4; ++_r) {                  \
        _p[_r] = __expf(_p[_r] - _mx); _sum += _p[_r]; }                  \
      _sum += __shfl_xor(_sum, 16, 64);                                   \
      _sum += __shfl_xor(_sum, 32, 64);                                   \
      float _inv = 1.0f / _sum;                                           \
      _Pragma("unroll") for (int _r = 0; _r < 4; ++_r) _p[_r] *= _inv;    \
      bf16x8 _pa;                                                         \
      _Pragma("unroll") for (int _j = 0; _j < 8; ++_j) {                  \
        float _v = __shfl(_p[_j & 3], li + 16 * (2 * lq + (_j >> 2)), 64);\
        _pa[_j] = (lq < 2) ? f2bf(_v) : (short)0;                         \
      }                                                                   \
      bf16x8 _vb = B0;                                                    \
      if (lq < 2) _vb = *(const bf16x8*)((MYK) + (_h * 16 + li) * 16 + lq * 8); \
      f32x4 _o = mfma16(_pa, _vb, F0);                                    \
      _Pragma("unroll") for (int _r = 0; _r < 4; ++_r)                    \
        tile_st16((MYQ), lq * 4 + _r, _h * 16 + li, f2bf(_o[_r]));        \
    }                                                                     \
    LDS_FENCE();                                                          \
    _Pragma("unroll") for (int _s = 0; _s < 4; ++_s)                      \
      (OA)[_s] = tile_ld8((MYQ), li, _s * 32 + lq * 8);                   \
  } while (0)

// ---- prep: transpose + fp32->bf16 all weight matrices into ws ----
__global__ void prep_kernel(const float* __restrict__ ew, const float* __restrict__ wq,
                            const float* __restrict__ wk, const float* __restrict__ wv,
                            const float* __restrict__ afc, const float* __restrict__ w1,
                            const float* __restrict__ w2, const float* __restrict__ f2n,
                            short* __restrict__ wsb) {
  int tt = blockIdx.x * 256 + threadIdx.x;
  if (tt >= TOTAL_W) return;
  short v;
  if (tt < OFF_WQT) {                       // EWT [128][32] <- ew [32][128]
    int u = tt; int row = u >> 5, colr = u & 31;
    v = f2bf(ew[colr * 128 + row]);
  } else if (tt < OFF_WKT) {                // WQT [2][128][128]
    int u = tt - OFF_WQT; int i = u >> 14; u &= 16383; int row = u >> 7, colr = u & 127;
    v = f2bf(wq[i * 16384 + colr * 128 + row]);
  } else if (tt < OFF_WVT) {
    int u = tt - OFF_WKT; int i = u >> 14; u &= 16383; int row = u >> 7, colr = u & 127;
    v = f2bf(wk[i * 16384 + colr * 128 + row]);
  } else if (tt < OFF_AFT) {
    int u = tt - OFF_WVT; int i = u >> 14; u &= 16383; int row = u >> 7, colr = u & 127;
    v = f2bf(wv[i * 16384 + colr * 128 + row]);
  } else if (tt < OFF_W1T) {                // AFT [2][128][128]
    int u = tt - OFF_AFT; int i = u >> 14; u &= 16383; int row = u >> 7, colr = u & 127;
    v = f2bf(afc[i * 16384 + colr * 128 + row]);
  } else if (tt < OFF_W2T) {                // W1T [2][512][128] <- w1 [2][128][512]
    int u = tt - OFF_W1T; int i = u >> 16; u &= 65535; int row = u >> 7, colr = u & 127;
    v = f2bf(w1[i * 65536 + colr * 512 + row]);
  } else if (tt < OFF_F2N) {                // W2T [2][128][512] <- w2 [2][512][128]
    int u = tt - OFF_W2T; int i = u >> 16; u &= 65535; int row = u >> 9, colr = u & 511;
    v = f2bf(w2[i * 65536 + colr * 128 + row]);
  } else {                                  // F2N [128][128] <- f2n [128][128]
    int u = tt - OFF_F2N; int row = u >> 7, colr = u & 127;
    v = f2bf(f2n[colr * 128 + row]);
  }
  wsb[tt] = v;
}

// ======== attention-half kernel (unchanged from r18) ========
__global__ __launch_bounds__(512, 2) void attn_kernel(
    const float* __restrict__ node_h, const int* __restrict__ src_idx,
    const float* __restrict__ edge_feat, const float* __restrict__ t_arr,
    const float* __restrict__ t_now, const float* __restrict__ edge_fc_b,
    const float* __restrict__ basis_freq, const float* __restrict__ phase,
    const float* __restrict__ attn_fc_b, const float* __restrict__ attn_ln_g,
    const float* __restrict__ attn_ln_b, const short* __restrict__ wsb,
    short* __restrict__ fbuf, int il, int do_msg) {
  __shared__ __align__(16) short bufs0[8192];   // 16KB half A
  __shared__ __align__(16) short bufs1[8192];   // 16KB half B
  __shared__ __align__(16) short qk[8][4096];   // per-wave Q(2048)+K(2048)

  const int tid = (int)threadIdx.x;
  const int w = tid >> 6, lane = tid & 63, li = lane & 15, lq = lane >> 4;
  const int n = (int)blockIdx.x * 8 + w;
  short* myQ = qk[w];
  short* myK = qk[w] + 2048;
  short* bc = bufs0;
  short* bn = bufs1;
  const f32x4 F0 = {0.f, 0.f, 0.f, 0.f};
  const bf16x8 B0 = {0, 0, 0, 0, 0, 0, 0, 0};
  const short* WQT = wsb + OFF_WQT + il * 16384;
  const short* WKT = wsb + OFF_WKT + il * 16384;
  const short* WVT = wsb + OFF_WVT + il * 16384;
  const short* AFT = wsb + OFF_AFT + il * 16384;

  stage_h8(bc, WQT, 128, w, lane);   // prologue: WQ h0 (rows 0..63)

  f32x4 acc[8];
  if (do_msg) {
    const float tnow = t_now[0];
    {
      const float* ef = edge_feat + ((size_t)(n * 16 + li)) * 32 + lq * 8;
      f32x4 e0 = *(const f32x4*)(ef);
      f32x4 e1 = *(const f32x4*)(ef + 4);
      bf16x8 ea;
      #pragma unroll
      for (int j = 0; j < 4; ++j) { ea[j] = f2bf(e0[j]); ea[j + 4] = f2bf(e1[j]); }
      const short* ewt = wsb + OFF_EWT;
      #pragma unroll
      for (int c = 0; c < 8; ++c) {
        bf16x8 eb = *(const bf16x8*)(ewt + (c * 16 + li) * 32 + lq * 8);
        acc[c] = mfma16(ea, eb, F0);
      }
    }
    {
      float bfq[8], phs[8], ebs[8];
      #pragma unroll
      for (int c = 0; c < 8; ++c) {
        int col = c * 16 + li;
        bfq[c] = basis_freq[col]; phs[c] = phase[col]; ebs[c] = edge_fc_b[col];
      }
      #pragma unroll
      for (int r = 0; r < 4; ++r) {
        int m = lq * 4 + r;
        int sidx = src_idx[n * 16 + m];
        float dt = tnow - t_arr[n * 16 + m];
        const float* nh = node_h + (size_t)sidx * 128;
        #pragma unroll
        for (int c = 0; c < 8; ++c) {
          int col = c * 16 + li;
          float x = gelu_f(acc[c][r] + ebs[c]);
          x += nh[col];
          x += __cosf(dt * bfq[c] + phs[c]);
          acc[c][r] = x;
        }
      }
    }
    ST_TILE(myQ, acc);
  } else {
    stage_f(myQ, fbuf + (size_t)n * 2048, lane);
  }
  __syncthreads();   // prologue stage + f tiles ready
  if (!do_msg) {
    #pragma unroll
    for (int c = 0; c < 8; ++c)
      #pragma unroll
      for (int r = 0; r < 4; ++r)
        acc[c][r] = tile_ldf(myQ, lq * 4 + r, c * 16 + li);
  }

  bf16x8 fA[4], oa_[4];

  // WQ halves
  #pragma unroll
  for (int h = 0; h < 2; ++h) {
    const short* nx = (h == 0) ? (WQT + 8192) : WKT;
    stage_h8(bn, nx, 128, w, lane);
    if (h == 0) LD_FA(myQ);
    { PROJ4H(bc, 0); ST4H(myQ, h); }
    ENDSTEP();
  }
  // WK halves
  #pragma unroll
  for (int h = 0; h < 2; ++h) {
    const short* nx = (h == 0) ? (WKT + 8192) : WVT;
    stage_h8(bn, nx, 128, w, lane);
    { PROJ4H(bc, 0); ST4H(myK, h); }
    ENDSTEP();
  }
  // WV halves (+ attention at h1)
  {
    f32x4 vacc[8];
    #pragma unroll
    for (int h = 0; h < 2; ++h) {
      const short* nx = (h == 0) ? (WVT + 8192) : AFT;
      stage_h8(bn, nx, 128, w, lane);
      {
        PROJ4H(bc, 0);
        vacc[h * 4 + 0] = g0; vacc[h * 4 + 1] = g1;
        vacc[h * 4 + 2] = g2; vacc[h * 4 + 3] = g3;
      }
      if (h == 1) {
        LDS_FENCE();
        ATTN(myQ, myK, vacc, oa_);
      }
      ENDSTEP();
    }
  }
  // AF halves
  #pragma unroll
  for (int h = 0; h < 2; ++h) {
    if (h == 0) stage_h8(bn, AFT + 8192, 128, w, lane);
    #pragma unroll
    for (int j = 0; j < 4; ++j) {
      float b = attn_fc_b[il * 128 + (h * 4 + j) * 16 + li];
      #pragma unroll
      for (int r = 0; r < 4; ++r) acc[h * 4 + j][r] += b;
    }
    ACC4H(oa_, h * 4, bc, 0);
    if (h == 1) {
      LAYER_NORM(acc, attn_ln_g + il * 128, attn_ln_b + il * 128);
      ST_TILE(myQ, acc);
    }
    ENDSTEP();
  }
  // epilogue: coalesced f' store
  LDS_FENCE();
  #pragma unroll
  for (int j = 0; j < 4; ++j) {
    int row = lane >> 2, colb = (lane & 3) * 32 + j * 8;
    bf16x8 v = tile_ld8(myQ, row, colb);
    *(bf16x8*)(fbuf + (size_t)n * 2048 + row * 128 + colb) = v;
  }
}

// ======== FFN-half kernel: 4 waves x 2 nodes, 16KB half stages, 512-reg budget ========
__global__ __launch_bounds__(256, 1) void ffn_kernel(
    const float* __restrict__ ffn_b1, const float* __restrict__ ffn_b2,
    const float* __restrict__ ffn_ln_g, const float* __restrict__ ffn_ln_b,
    const float* __restrict__ f2n_b, const float* __restrict__ fin_g,
    const float* __restrict__ fin_b, const float* __restrict__ node_h,
    const short* __restrict__ wsb, short* __restrict__ fbuf,
    float* __restrict__ out, int il, int last) {
  __shared__ __align__(16) short bufs0[8192];    // 16KB half A
  __shared__ __align__(16) short bufs1[8192];    // 16KB half B
  __shared__ __align__(16) short tiles[4][4096]; // per-wave t0(2048)+t1(2048)

  const int tid = (int)threadIdx.x;
  const int w = tid >> 6, lane = tid & 63, li = lane & 15, lq = lane >> 4;
  const int n0 = (int)blockIdx.x * 8 + w * 2, n1 = n0 + 1;
  short* t0 = tiles[w];
  short* t1 = tiles[w] + 2048;
  short* bc = bufs0;
  short* bn = bufs1;
  const f32x4 F0 = {0.f, 0.f, 0.f, 0.f};
  const short* W1T = wsb + OFF_W1T + il * 65536;
  const short* W2T = wsb + OFF_W2T + il * 65536;

  stage_h4(bc, W1T, 128, w, lane);     // prologue: W1 ct0 rows 0..63
  stage_f(t0, fbuf + (size_t)n0 * 2048, lane);
  stage_f(t1, fbuf + (size_t)n1 * 2048, lane);
  __syncthreads();

  bf16x8 fA0[4], fA1[4], ha0_[4], ha1_[4];
  #pragma unroll
  for (int s = 0; s < 4; ++s) {
    fA0[s] = tile_ld8(t0, li, s * 32 + lq * 8);
    fA1[s] = tile_ld8(t1, li, s * 32 + lq * 8);
  }
  f32x4 acc0[8], acc1[8];
  #pragma unroll
  for (int c = 0; c < 8; ++c) {
    float b2 = ffn_b2[il * 128 + c * 16 + li];
    #pragma unroll
    for (int r = 0; r < 4; ++r) {
      acc0[c][r] = tile_ldf(t0, lq * 4 + r, c * 16 + li) + b2;
      acc1[c][r] = tile_ldf(t1, lq * 4 + r, c * 16 + li) + b2;
    }
  }
  LDS_FENCE();   // f reads complete before hid overwrites t0/t1

  for (int ct = 0; ct < 4; ++ct) {
    const short* W1c = W1T + ct * 16384;
    const short* W2c = W2T + ct * 128;
    const float* b1p = ffn_b1 + il * 512 + ct * 128;
    // W1 halves -> hid tiles
    #pragma unroll
    for (int h = 0; h < 2; ++h) {
      const short* nx = (h == 0) ? (W1c + 64 * 128) : W2c;
      stage_h4(bn, nx, (h == 0) ? 128 : 512, w, lane);
      {
        PROJ2H(bc);
        float b1v[4];
        #pragma unroll
        for (int j = 0; j < 4; ++j) b1v[j] = b1p[(h * 4 + j) * 16 + li];
        #pragma unroll
        for (int r = 0; r < 4; ++r) {
          tile_st16(t0, lq * 4 + r, (h * 4 + 0) * 16 + li, f2bf(fmaxf(ga0[r] + b1v[0], 0.f)));
          tile_st16(t0, lq * 4 + r, (h * 4 + 1) * 16 + li, f2bf(fmaxf(ga1[r] + b1v[1], 0.f)));
          tile_st16(t0, lq * 4 + r, (h * 4 + 2) * 16 + li, f2bf(fmaxf(ga2[r] + b1v[2], 0.f)));
          tile_st16(t0, lq * 4 + r, (h * 4 + 3) * 16 + li, f2bf(fmaxf(ga3[r] + b1v[3], 0.f)));
          tile_st16(t1, lq * 4 + r, (h * 4 + 0) * 16 + li, f2bf(fmaxf(gb0[r] + b1v[0], 0.f)));
          tile_st16(t1, lq * 4 + r, (h * 4 + 1) * 16 + li, f2bf(fmaxf(gb1[r] + b1v[1], 0.f)));
          tile_st16(t1, lq * 4 + r, (h * 4 + 2) * 16 + li, f2bf(fmaxf(gb2[r] + b1v[2], 0.f)));
          tile_st16(t1, lq * 4 + r, (h * 4 + 3) * 16 + li, f2bf(fmaxf(gb3[r] + b1v[3], 0.f)));
        }
      }
      if (h == 1) {
        LDS_FENCE();
        #pragma unroll
        for (int s = 0; s < 4; ++s) {
          ha0_[s] = tile_ld8(t0, li, s * 32 + lq * 8);
          ha1_[s] = tile_ld8(t1, li, s * 32 + lq * 8);
        }
      }
      ENDSTEP();
    }
    // W2 halves (out-col groups of 64)
    #pragma unroll
    for (int h = 0; h < 2; ++h) {
      if (h == 0) stage_h4(bn, W2c + 64 * 512, 512, w, lane);
      else if (ct < 3) stage_h4(bn, W1T + (ct + 1) * 16384, 128, w, lane);
      ACC2H(ha0_, ha1_, h * 4, bc);
      if (ct == 3 && h == 1) {
        LAYER_NORM(acc0, ffn_ln_g + il * 128, ffn_ln_b + il * 128);
        LAYER_NORM(acc1, ffn_ln_g + il * 128, ffn_ln_b + il * 128);
      }
      ENDSTEP();
    }
  }

  if (last) {
    // pooling + fea2node + final LN for both nodes (t0/t1 dead -> float scratch)
    float pc0[8], pc1[8];
    #pragma unroll
    for (int c = 0; c < 8; ++c) {
      float s0 = acc0[c][0] + acc0[c][1] + acc0[c][2] + acc0[c][3];
      float s1 = acc1[c][0] + acc1[c][1] + acc1[c][2] + acc1[c][3];
      s0 += __shfl_xor(s0, 16, 64); s0 += __shfl_xor(s0, 32, 64);
      s1 += __shfl_xor(s1, 16, 64); s1 += __shfl_xor(s1, 32, 64);
      pc0[c] = s0 * (1.f / 16.f);
      pc1[c] = s1 * (1.f / 16.f);
    }
    float* ps0 = (float*)t0;
    float* ps1 = (float*)t1;
    if (lq == 0) {
      #pragma unroll
      for (int c = 0; c < 8; ++c) { ps0[c * 16 + li] = pc0[c]; ps1[c * 16 + li] = pc1[c]; }
    }
    LDS_FENCE();
    const short* F2NT = wsb + OFF_F2N;
    #pragma unroll
    for (int nd = 0; nd < 2; ++nd) {
      const float* ps = nd ? ps1 : ps0;
      int n = nd ? n1 : n0;
      float yv[2];
      #pragma unroll
      for (int half = 0; half < 2; ++half) {
        int col = half * 64 + lane;
        float dot = 0.f;
        for (int d0 = 0; d0 < 128; d0 += 8) {
          bf16x8 wv8 = *(const bf16x8*)(F2NT + col * 128 + d0);
          f32x4 p0 = *(const f32x4*)(ps + d0);
          f32x4 p1 = *(const f32x4*)(ps + d0 + 4);
          dot += p0[0] * bf2f(wv8[0]) + p0[1] * bf2f(wv8[1]) + p0[2] * bf2f(wv8[2]) + p0[3] * bf2f(wv8[3]);
          dot += p1[0] * bf2f(wv8[4]) + p1[1] * bf2f(wv8[5]) + p1[2] * bf2f(wv8[6]) + p1[3] * bf2f(wv8[7]);
        }
        yv[half] = gelu_f(dot + f2n_b[col]) + node_h[(size_t)n * 128 + col];
      }
      float s1v = yv[0] + yv[1], s2v = yv[0] * yv[0] + yv[1] * yv[1];
      #pragma unroll
      for (int m = 1; m <= 32; m <<= 1) {
        s1v += __shfl_xor(s1v, m, 64); s2v += __shfl_xor(s2v, m, 64);
      }
      float mean = s1v * (1.f / 128.f);
      float var = s2v * (1.f / 128.f) - mean * mean;
      float rstd = rsqrtf(var + 1e-5f);
      #pragma unroll
      for (int half = 0; half < 2; ++half) {
        int col = half * 64 + lane;
        out[(size_t)n * 128 + col] = (yv[half] - mean) * rstd * fin_g[col] + fin_b[col];
      }
    }
  } else {
    ST_TILE(t0, acc0);   // hid dead; transpose f' through tiles
    ST_TILE(t1, acc1);
    LDS_FENCE();
    #pragma unroll
    for (int j = 0; j < 4; ++j) {
      int row = lane >> 2, colb = (lane & 3) * 32 + j * 8;
      bf16x8 v0 = tile_ld8(t0, row, colb);
      bf16x8 v1 = tile_ld8(t1, row, colb);
      *(bf16x8*)(fbuf + (size_t)n0 * 2048 + row * 128 + colb) = v0;
      *(bf16x8*)(fbuf + (size_t)n1 * 2048 + row * 128 + colb) = v1;
    }
  }
}

extern "C" void kernel_launch(void* const* d_in, const int* in_sizes, int n_in,
                              void* d_out, int out_size, void* d_ws, size_t ws_size,
                              hipStream_t stream) {
  const float* node_h    = (const float*)d_in[0];
  const int*   src_idx   = (const int*)d_in[1];
  const float* edge_feat = (const float*)d_in[2];
  const float* t_arr     = (const float*)d_in[3];
  const float* t_now     = (const float*)d_in[4];
  const float* edge_fc_w = (const float*)d_in[5];
  const float* edge_fc_b = (const float*)d_in[6];
  const float* basis_frq = (const float*)d_in[7];
  const float* phase     = (const float*)d_in[8];
  const float* wq        = (const float*)d_in[9];
  const float* wk        = (const float*)d_in[10];
  const float* wv        = (const float*)d_in[11];
  const float* attn_fc_w = (const float*)d_in[12];
  const float* attn_fc_b = (const float*)d_in[13];
  const float* attn_ln_g = (const float*)d_in[14];
  const float* attn_ln_b = (const float*)d_in[15];
  const float* ffn_w1    = (const float*)d_in[16];
  const float* ffn_b1    = (const float*)d_in[17];
  const float* ffn_w2    = (const float*)d_in[18];
  const float* ffn_b2    = (const float*)d_in[19];
  const float* ffn_ln_g  = (const float*)d_in[20];
  const float* ffn_ln_b  = (const float*)d_in[21];
  const float* f2n_w     = (const float*)d_in[22];
  const float* f2n_b     = (const float*)d_in[23];
  const float* fin_g     = (const float*)d_in[24];
  const float* fin_b     = (const float*)d_in[25];
  short* wsb  = (short*)d_ws;
  short* fbuf = (short*)((char*)d_ws + FB_BYTE_OFF);

  prep_kernel<<<(TOTAL_W + 255) / 256, 256, 0, stream>>>(
      edge_fc_w, wq, wk, wv, attn_fc_w, ffn_w1, ffn_w2, f2n_w, wsb);
  attn_kernel<<<NN / 8, 512, 0, stream>>>(
      node_h, src_idx, edge_feat, t_arr, t_now, edge_fc_b, basis_frq, phase,
      attn_fc_b, attn_ln_g, attn_ln_b, wsb, fbuf, 0, 1);
  ffn_kernel<<<NN / 8, 256, 0, stream>>>(
      ffn_b1, ffn_b2, ffn_ln_g, ffn_ln_b, f2n_b, fin_g, fin_b, node_h,
      wsb, fbuf, (float*)d_out, 0, 0);
  attn_kernel<<<NN / 8, 512, 0, stream>>>(
      node_h, src_idx, edge_feat, t_arr, t_now, edge_fc_b, basis_frq, phase,
      attn_fc_b, attn_ln_g, attn_ln_b, wsb, fbuf, 1, 0);
  ffn_kernel<<<NN / 8, 256, 0, stream>>>(
      ffn_b1, ffn_b2, ffn_ln_g, ffn_ln_b, f2n_b, fin_g, fin_b, node_h,
      wsb, fbuf, (float*)d_out, 1, 1);
}

// Round 20
// 635.219 us; speedup vs baseline: 1.0883x; 1.0883x over previous
//
#include <hip/hip_runtime.h>

// Problem constants
#define NN 16384
// ws (bf16) region offsets, in elements
#define OFF_EWT 0
#define OFF_WQT 4096
#define OFF_WKT 36864
#define OFF_WVT 69632
#define OFF_AFT 102400
#define OFF_W1T 135168
#define OFF_W2T 266240
#define OFF_F2N 397312
#define TOTAL_W 413696
#define FB_BYTE_OFF (1 << 20)   // fbuf starts 1MB into d_ws; 16384 nodes x 4KB = 64MB

typedef __attribute__((ext_vector_type(8))) short bf16x8;
typedef __attribute__((ext_vector_type(4))) short bf16x4;
typedef __attribute__((ext_vector_type(4))) float f32x4;

static __device__ __forceinline__ short f2bf(float f) {
  unsigned u = __builtin_bit_cast(unsigned, f);
  u += 0x7fffu + ((u >> 16) & 1u);           // RNE
  return (short)(u >> 16);
}
static __device__ __forceinline__ float bf2f(short h) {
  unsigned u = ((unsigned)(unsigned short)h) << 16;
  return __builtin_bit_cast(float, u);
}
static __device__ __forceinline__ float gelu_f(float x) {
  float e = __expf(1.5957691216057308f * (x + 0.044715f * x * x * x));
  return x - x / (e + 1.0f);
}
static __device__ __forceinline__ f32x4 mfma16(bf16x8 a, bf16x8 b, f32x4 c) {
  return __builtin_amdgcn_mfma_f32_16x16x32_bf16(a, b, c, 0, 0, 0);
}
// XOR bank swizzle
#define SWZM(row) (((((row) & 7) << 4)) ^ ((((row) >> 3) & 3) << 5))
static __device__ __forceinline__ int swzb(int row, int col) {
  return row * 256 + ((col * 2) ^ SWZM(row));
}
static __device__ __forceinline__ bf16x8 tile_ld8(const short* base, int row, int col) {
  return *(const bf16x8*)((const char*)base + swzb(row, col));
}
static __device__ __forceinline__ void tile_st16(short* base, int row, int col, short v) {
  *(short*)((char*)base + swzb(row, col)) = v;
}
static __device__ __forceinline__ float tile_ldf(const short* base, int row, int col) {
  return bf2f(*(const short*)((const char*)base + swzb(row, col)));
}
static __device__ __forceinline__ void gll16(const short* sp, void* dstb) {
  __builtin_amdgcn_global_load_lds(
      (const __attribute__((address_space(1))) unsigned int*)sp,
      (__attribute__((address_space(3))) unsigned int*)dstb, 16, 0, 0);
}
// 16KB half stage for 8-wave WGs: 2 gll16 per wave (64 rows x 128)
static __device__ __forceinline__ void stage_h8(short* dst, const short* src, int stride,
                                                int w, int lane) {
  #pragma unroll
  for (int it = 0; it < 2; ++it) {
    int dbase = (it * 8 + w) * 1024;
    int d = dbase + lane * 16;
    int row = d >> 8;                        // 0..63
    int scolb = (d & 255) ^ SWZM(row);
    gll16(src + row * stride + (scolb >> 1), (char*)dst + dbase);
  }
}
// 32KB full-tile stage for 8-wave WGs (ffn): 4 gll16 per wave (128 rows x 128)
static __device__ __forceinline__ void stage_full8(short* dst, const short* src, int stride,
                                                   int w, int lane) {
  #pragma unroll
  for (int it = 0; it < 4; ++it) {
    int dbase = (it * 8 + w) * 1024;
    int d = dbase + lane * 16;
    int row = d >> 8;                        // 0..127
    int scolb = (d & 255) ^ SWZM(row);
    gll16(src + row * stride + (scolb >> 1), (char*)dst + dbase);
  }
}
// 4KB f-tile stage (16 rows x 128), per wave into its own tile
static __device__ __forceinline__ void stage_f(short* dst, const short* src, int lane) {
  #pragma unroll
  for (int it = 0; it < 4; ++it) {
    int dbase = it * 1024;
    int d = dbase + lane * 16;
    int row = d >> 8;                        // 0..15
    int scolb = (d & 255) ^ SWZM(row);
    gll16(src + row * 128 + (scolb >> 1), (char*)dst + dbase);
  }
}

#define LDS_FENCE() do {                                       \
    asm volatile("s_waitcnt lgkmcnt(0)" ::: "memory");         \
    __builtin_amdgcn_sched_barrier(0);                         \
  } while (0)

#define ENDSTEP() do {                                         \
    __syncthreads();                                           \
    short* _t = bc; bc = bn; bn = _t;                          \
  } while (0)

#define LD_FA(SRC)                                                        \
  _Pragma("unroll") for (int _s = 0; _s < 4; ++_s)                        \
      fA[_s] = tile_ld8((SRC), li, _s * 32 + lq * 8);

#define ST_TILE(T, ACC)                                                   \
  _Pragma("unroll") for (int _c = 0; _c < 8; ++_c)                        \
    _Pragma("unroll") for (int _r = 0; _r < 4; ++_r)                      \
      tile_st16((T), lq * 4 + _r, _c * 16 + li, f2bf((ACC)[_c][_r]));

// 64-row half projection with row offset: 16 B-frag reads feed 16 MFMAs
#define PROJ4H(BB, RO)                                                    \
    f32x4 g0 = F0, g1 = F0, g2 = F0, g3 = F0;                             \
    _Pragma("unroll") for (int _s = 0; _s < 4; ++_s) {                    \
      int _sc = _s * 32 + lq * 8;                                         \
      g0 = mfma16(fA[_s], tile_ld8((BB), (RO) + 0 + li, _sc), g0);        \
      g1 = mfma16(fA[_s], tile_ld8((BB), (RO) + 16 + li, _sc), g1);       \
      g2 = mfma16(fA[_s], tile_ld8((BB), (RO) + 32 + li, _sc), g2);       \
      g3 = mfma16(fA[_s], tile_ld8((BB), (RO) + 48 + li, _sc), g3);       \
    }

// store the 4 half-projection tiles into DST at col-block base HB*4
#define ST4H(DST, HB)                                                     \
    _Pragma("unroll") for (int _r = 0; _r < 4; ++_r) {                    \
      tile_st16((DST), lq * 4 + _r, ((HB) * 4 + 0) * 16 + li, f2bf(g0[_r])); \
      tile_st16((DST), lq * 4 + _r, ((HB) * 4 + 1) * 16 + li, f2bf(g1[_r])); \
      tile_st16((DST), lq * 4 + _r, ((HB) * 4 + 2) * 16 + li, f2bf(g2[_r])); \
      tile_st16((DST), lq * 4 + _r, ((HB) * 4 + 3) * 16 + li, f2bf(g3[_r])); \
    }

// half accumulate with row offset: acc[CB..CB+3] += A * staged rows RO..RO+63
#define ACC4H(AR, CB, BB, RO)                                             \
    _Pragma("unroll") for (int _s = 0; _s < 4; ++_s) {                    \
      int _sc = _s * 32 + lq * 8;                                         \
      acc[(CB) + 0] = mfma16(AR[_s], tile_ld8((BB), (RO) + 0 + li, _sc), acc[(CB) + 0]);  \
      acc[(CB) + 1] = mfma16(AR[_s], tile_ld8((BB), (RO) + 16 + li, _sc), acc[(CB) + 1]); \
      acc[(CB) + 2] = mfma16(AR[_s], tile_ld8((BB), (RO) + 32 + li, _sc), acc[(CB) + 2]); \
      acc[(CB) + 3] = mfma16(AR[_s], tile_ld8((BB), (RO) + 48 + li, _sc), acc[(CB) + 3]); \
    }

#define LAYER_NORM(A, GP, BP) do {                                        \
    float _gg[8], _bb[8];                                                 \
    _Pragma("unroll") for (int _c = 0; _c < 8; ++_c) {                    \
      _gg[_c] = (GP)[_c * 16 + li]; _bb[_c] = (BP)[_c * 16 + li]; }       \
    _Pragma("unroll") for (int _r = 0; _r < 4; ++_r) {                    \
      float _s1 = 0.f, _s2 = 0.f;                                         \
      _Pragma("unroll") for (int _c = 0; _c < 8; ++_c) {                  \
        float _v = (A)[_c][_r]; _s1 += _v; _s2 += _v * _v; }              \
      _Pragma("unroll") for (int _m = 1; _m <= 8; _m <<= 1) {             \
        _s1 += __shfl_xor(_s1, _m, 64); _s2 += __shfl_xor(_s2, _m, 64); } \
      float _mean = _s1 * (1.f / 128.f);                                  \
      float _var = _s2 * (1.f / 128.f) - _mean * _mean;                   \
      float _rstd = rsqrtf(_var + 1e-5f);                                 \
      _Pragma("unroll") for (int _c = 0; _c < 8; ++_c)                    \
        (A)[_c][_r] = ((A)[_c][_r] - _mean) * _rstd * _gg[_c] + _bb[_c];  \
    }                                                                     \
  } while (0)

// wave-private attention; overlays Vt->MYK, Os->MYQ (both dead)
#define ATTN(MYQ, MYK, VACC, OA) do {                                     \
    f32x4 _st[8];                                                         \
    _Pragma("unroll") for (int _h = 0; _h < 8; ++_h) {                    \
      bf16x8 _ka = B0, _qa = B0;                                          \
      if (lq < 2) {                                                       \
        _ka = tile_ld8((MYK), li, _h * 16 + lq * 8);                      \
        _qa = tile_ld8((MYQ), li, _h * 16 + lq * 8);                      \
      }                                                                   \
      _st[_h] = mfma16(_ka, _qa, F0);                                     \
    }                                                                     \
    LDS_FENCE();                                                          \
    _Pragma("unroll") for (int _c = 0; _c < 8; ++_c) {                    \
      bf16x4 _pk;                                                         \
      _Pragma("unroll") for (int _r = 0; _r < 4; ++_r)                    \
        _pk[_r] = f2bf((VACC)[_c][_r]);                                   \
      *(bf16x4*)((MYK) + (_c * 16 + li) * 16 + lq * 4) = _pk;             \
    }                                                                     \
    LDS_FENCE();                                                          \
    _Pragma("unroll") for (int _h = 0; _h < 8; ++_h) {                    \
      float _p[4]; float _mx = -1e30f;                                    \
      _Pragma("unroll") for (int _r = 0; _r < 4; ++_r) {                  \
        _p[_r] = _st[_h][_r] * 0.25f; _mx = fmaxf(_mx, _p[_r]); }         \
      _mx = fmaxf(_mx, __shfl_xor(_mx, 16, 64));                          \
      _mx = fmaxf(_mx, __shfl_xor(_mx, 32, 64));                          \
      float _sum = 0.f;                                                   \
      _Pragma("unroll") for (int _r = 0; _r < 4; ++_r) {                  \
        _p[_r] = __expf(_p[_r] - _mx); _sum += _p[_r]; }                  \
      _sum += __shfl_xor(_sum, 16, 64);                                   \
      _sum += __shfl_xor(_sum, 32, 64);                                   \
      float _inv = 1.0f / _sum;                                           \
      _Pragma("unroll") for (int _r = 0; _r < 4; ++_r) _p[_r] *= _inv;    \
      bf16x8 _pa;                                                         \
      _Pragma("unroll") for (int _j = 0; _j < 8; ++_j) {                  \
        float _v = __shfl(_p[_j & 3], li + 16 * (2 * lq + (_j >> 2)), 64);\
        _pa[_j] = (lq < 2) ? f2bf(_v) : (short)0;                         \
      }                                                                   \
      bf16x8 _vb = B0;                                                    \
      if (lq < 2) _vb = *(const bf16x8*)((MYK) + (_h * 16 + li) * 16 + lq * 8); \
      f32x4 _o = mfma16(_pa, _vb, F0);                                    \
      _Pragma("unroll") for (int _r = 0; _r < 4; ++_r)                    \
        tile_st16((MYQ), lq * 4 + _r, _h * 16 + li, f2bf(_o[_r]));        \
    }                                                                     \
    LDS_FENCE();                                                          \
    _Pragma("unroll") for (int _s = 0; _s < 4; ++_s)                      \
      (OA)[_s] = tile_ld8((MYQ), li, _s * 32 + lq * 8);                   \
  } while (0)

// ---- prep: transpose + fp32->bf16 all weight matrices into ws ----
__global__ void prep_kernel(const float* __restrict__ ew, const float* __restrict__ wq,
                            const float* __restrict__ wk, const float* __restrict__ wv,
                            const float* __restrict__ afc, const float* __restrict__ w1,
                            const float* __restrict__ w2, const float* __restrict__ f2n,
                            short* __restrict__ wsb) {
  int tt = blockIdx.x * 256 + threadIdx.x;
  if (tt >= TOTAL_W) return;
  short v;
  if (tt < OFF_WQT) {                       // EWT [128][32] <- ew [32][128]
    int u = tt; int row = u >> 5, colr = u & 31;
    v = f2bf(ew[colr * 128 + row]);
  } else if (tt < OFF_WKT) {                // WQT [2][128][128]
    int u = tt - OFF_WQT; int i = u >> 14; u &= 16383; int row = u >> 7, colr = u & 127;
    v = f2bf(wq[i * 16384 + colr * 128 + row]);
  } else if (tt < OFF_WVT) {
    int u = tt - OFF_WKT; int i = u >> 14; u &= 16383; int row = u >> 7, colr = u & 127;
    v = f2bf(wk[i * 16384 + colr * 128 + row]);
  } else if (tt < OFF_AFT) {
    int u = tt - OFF_WVT; int i = u >> 14; u &= 16383; int row = u >> 7, colr = u & 127;
    v = f2bf(wv[i * 16384 + colr * 128 + row]);
  } else if (tt < OFF_W1T) {                // AFT [2][128][128]
    int u = tt - OFF_AFT; int i = u >> 14; u &= 16383; int row = u >> 7, colr = u & 127;
    v = f2bf(afc[i * 16384 + colr * 128 + row]);
  } else if (tt < OFF_W2T) {                // W1T [2][512][128] <- w1 [2][128][512]
    int u = tt - OFF_W1T; int i = u >> 16; u &= 65535; int row = u >> 7, colr = u & 127;
    v = f2bf(w1[i * 65536 + colr * 512 + row]);
  } else if (tt < OFF_F2N) {                // W2T [2][128][512] <- w2 [2][512][128]
    int u = tt - OFF_W2T; int i = u >> 16; u &= 65535; int row = u >> 9, colr = u & 511;
    v = f2bf(w2[i * 65536 + colr * 128 + row]);
  } else {                                  // F2N [128][128] <- f2n [128][128]
    int u = tt - OFF_F2N; int row = u >> 7, colr = u & 127;
    v = f2bf(f2n[colr * 128 + row]);
  }
  wsb[tt] = v;
}

// ======== attention-half kernel: 16KB half-tile stages (10 steps) ========
__global__ __launch_bounds__(512, 2) void attn_kernel(
    const float* __restrict__ node_h, const int* __restrict__ src_idx,
    const float* __restrict__ edge_feat, const float* __restrict__ t_arr,
    const float* __restrict__ t_now, const float* __restrict__ edge_fc_b,
    const float* __restrict__ basis_freq, const float* __restrict__ phase,
    const float* __restrict__ attn_fc_b, const float* __restrict__ attn_ln_g,
    const float* __restrict__ attn_ln_b, const short* __restrict__ wsb,
    short* __restrict__ fbuf, int il, int do_msg) {
  __shared__ __align__(16) short bufs0[8192];   // 16KB half A
  __shared__ __align__(16) short bufs1[8192];   // 16KB half B
  __shared__ __align__(16) short qk[8][4096];   // per-wave Q(2048)+K(2048)

  const int tid = (int)threadIdx.x;
  const int w = tid >> 6, lane = tid & 63, li = lane & 15, lq = lane >> 4;
  const int n = (int)blockIdx.x * 8 + w;
  short* myQ = qk[w];
  short* myK = qk[w] + 2048;
  short* bc = bufs0;
  short* bn = bufs1;
  const f32x4 F0 = {0.f, 0.f, 0.f, 0.f};
  const bf16x8 B0 = {0, 0, 0, 0, 0, 0, 0, 0};
  const short* WQT = wsb + OFF_WQT + il * 16384;
  const short* WKT = wsb + OFF_WKT + il * 16384;
  const short* WVT = wsb + OFF_WVT + il * 16384;
  const short* AFT = wsb + OFF_AFT + il * 16384;

  stage_h8(bc, WQT, 128, w, lane);   // prologue: WQ h0 (rows 0..63)

  f32x4 acc[8];
  if (do_msg) {
    const float tnow = t_now[0];
    {
      const float* ef = edge_feat + ((size_t)(n * 16 + li)) * 32 + lq * 8;
      f32x4 e0 = *(const f32x4*)(ef);
      f32x4 e1 = *(const f32x4*)(ef + 4);
      bf16x8 ea;
      #pragma unroll
      for (int j = 0; j < 4; ++j) { ea[j] = f2bf(e0[j]); ea[j + 4] = f2bf(e1[j]); }
      const short* ewt = wsb + OFF_EWT;
      #pragma unroll
      for (int c = 0; c < 8; ++c) {
        bf16x8 eb = *(const bf16x8*)(ewt + (c * 16 + li) * 32 + lq * 8);
        acc[c] = mfma16(ea, eb, F0);
      }
    }
    {
      float bfq[8], phs[8], ebs[8];
      #pragma unroll
      for (int c = 0; c < 8; ++c) {
        int col = c * 16 + li;
        bfq[c] = basis_freq[col]; phs[c] = phase[col]; ebs[c] = edge_fc_b[col];
      }
      #pragma unroll
      for (int r = 0; r < 4; ++r) {
        int m = lq * 4 + r;
        int sidx = src_idx[n * 16 + m];
        float dt = tnow - t_arr[n * 16 + m];
        const float* nh = node_h + (size_t)sidx * 128;
        #pragma unroll
        for (int c = 0; c < 8; ++c) {
          int col = c * 16 + li;
          float x = gelu_f(acc[c][r] + ebs[c]);
          x += nh[col];
          x += __cosf(dt * bfq[c] + phs[c]);
          acc[c][r] = x;
        }
      }
    }
    ST_TILE(myQ, acc);
  } else {
    stage_f(myQ, fbuf + (size_t)n * 2048, lane);
  }
  __syncthreads();   // prologue stage + f tiles ready
  if (!do_msg) {
    #pragma unroll
    for (int c = 0; c < 8; ++c)
      #pragma unroll
      for (int r = 0; r < 4; ++r)
        acc[c][r] = tile_ldf(myQ, lq * 4 + r, c * 16 + li);
  }

  bf16x8 fA[4], oa_[4];

  // WQ halves
  #pragma unroll
  for (int h = 0; h < 2; ++h) {
    const short* nx = (h == 0) ? (WQT + 8192) : WKT;
    stage_h8(bn, nx, 128, w, lane);
    if (h == 0) LD_FA(myQ);
    { PROJ4H(bc, 0); ST4H(myQ, h); }
    ENDSTEP();
  }
  // WK halves
  #pragma unroll
  for (int h = 0; h < 2; ++h) {
    const short* nx = (h == 0) ? (WKT + 8192) : WVT;
    stage_h8(bn, nx, 128, w, lane);
    { PROJ4H(bc, 0); ST4H(myK, h); }
    ENDSTEP();
  }
  // WV halves (+ attention at h1)
  {
    f32x4 vacc[8];
    #pragma unroll
    for (int h = 0; h < 2; ++h) {
      const short* nx = (h == 0) ? (WVT + 8192) : AFT;
      stage_h8(bn, nx, 128, w, lane);
      {
        PROJ4H(bc, 0);
        vacc[h * 4 + 0] = g0; vacc[h * 4 + 1] = g1;
        vacc[h * 4 + 2] = g2; vacc[h * 4 + 3] = g3;
      }
      if (h == 1) {
        LDS_FENCE();
        ATTN(myQ, myK, vacc, oa_);
      }
      ENDSTEP();
    }
  }
  // AF halves
  #pragma unroll
  for (int h = 0; h < 2; ++h) {
    if (h == 0) stage_h8(bn, AFT + 8192, 128, w, lane);
    #pragma unroll
    for (int j = 0; j < 4; ++j) {
      float b = attn_fc_b[il * 128 + (h * 4 + j) * 16 + li];
      #pragma unroll
      for (int r = 0; r < 4; ++r) acc[h * 4 + j][r] += b;
    }
    ACC4H(oa_, h * 4, bc, 0);
    if (h == 1) {
      LAYER_NORM(acc, attn_ln_g + il * 128, attn_ln_b + il * 128);
      ST_TILE(myQ, acc);
    }
    ENDSTEP();
  }
  // epilogue: coalesced f' store
  LDS_FENCE();
  #pragma unroll
  for (int j = 0; j < 4; ++j) {
    int row = lane >> 2, colb = (lane & 3) * 32 + j * 8;
    bf16x8 v = tile_ld8(myQ, row, colb);
    *(bf16x8*)(fbuf + (size_t)n * 2048 + row * 128 + colb) = v;
  }
}

// ======== FFN-half kernel: 8 waves x 1 node, 32KB full-tile stages ========
__global__ __launch_bounds__(512, 2) void ffn_kernel(
    const float* __restrict__ ffn_b1, const float* __restrict__ ffn_b2,
    const float* __restrict__ ffn_ln_g, const float* __restrict__ ffn_ln_b,
    const float* __restrict__ f2n_b, const float* __restrict__ fin_g,
    const float* __restrict__ fin_b, const float* __restrict__ node_h,
    const short* __restrict__ wsb, short* __restrict__ fbuf,
    float* __restrict__ out, int il, int last) {
  __shared__ __align__(16) short bufs0[16384];  // 32KB full tile A
  __shared__ __align__(16) short bufs1[16384];  // 32KB full tile B
  __shared__ __align__(16) short qk[8][2048];   // per-wave f/hid tile

  const int tid = (int)threadIdx.x;
  const int w = tid >> 6, lane = tid & 63, li = lane & 15, lq = lane >> 4;
  const int n = (int)blockIdx.x * 8 + w;
  short* myK = qk[w];                 // f' tile at entry, then hid tile
  short* bc = bufs0;
  short* bn = bufs1;
  const f32x4 F0 = {0.f, 0.f, 0.f, 0.f};
  const short* W1T = wsb + OFF_W1T + il * 65536;
  const short* W2T = wsb + OFF_W2T + il * 65536;

  stage_full8(bc, W1T, 128, w, lane);   // prologue: W1 ct0 full tile
  stage_f(myK, fbuf + (size_t)n * 2048, lane);
  __syncthreads();

  bf16x8 fA[4], ha_[4];
  LD_FA(myK);
  f32x4 acc[8];
  #pragma unroll
  for (int c = 0; c < 8; ++c) {
    float b2 = ffn_b2[il * 128 + c * 16 + li];
    #pragma unroll
    for (int r = 0; r < 4; ++r)
      acc[c][r] = tile_ldf(myK, lq * 4 + r, c * 16 + li) + b2;
  }
  LDS_FENCE();   // f reads complete before hid overwrites myK

  for (int ct = 0; ct < 4; ++ct) {
    const short* W1c = W1T + ct * 16384;
    const short* W2c = W2T + ct * 128;
    const float* b1p = ffn_b1 + il * 512 + ct * 128;
    // step A: W1 full tile -> hid (two sub-phases, no barrier between)
    stage_full8(bn, W2c, 512, w, lane);
    #pragma unroll
    for (int h = 0; h < 2; ++h) {
      PROJ4H(bc, h * 64);
      #pragma unroll
      for (int j = 0; j < 4; ++j) {
        float b1 = b1p[(h * 4 + j) * 16 + li];
        f32x4 gx = j == 0 ? g0 : j == 1 ? g1 : j == 2 ? g2 : g3;
        #pragma unroll
        for (int r = 0; r < 4; ++r)
          tile_st16(myK, lq * 4 + r, (h * 4 + j) * 16 + li, f2bf(fmaxf(gx[r] + b1, 0.f)));
      }
    }
    LDS_FENCE();
    #pragma unroll
    for (int s = 0; s < 4; ++s) ha_[s] = tile_ld8(myK, li, s * 32 + lq * 8);
    ENDSTEP();
    // step B: W2 full tile -> acc (two sub-phases)
    if (ct < 3) stage_full8(bn, W1T + (ct + 1) * 16384, 128, w, lane);
    ACC4H(ha_, 0, bc, 0);
    ACC4H(ha_, 4, bc, 64);
    if (ct == 3)
      LAYER_NORM(acc, ffn_ln_g + il * 128, ffn_ln_b + il * 128);
    ENDSTEP();
  }

  if (last) {
    // pooling + fea2node + final LN  (myK dead, reuse as float scratch)
    float pc[8];
    #pragma unroll
    for (int c = 0; c < 8; ++c) {
      float s = acc[c][0] + acc[c][1] + acc[c][2] + acc[c][3];
      s += __shfl_xor(s, 16, 64);
      s += __shfl_xor(s, 32, 64);
      pc[c] = s * (1.f / 16.f);
    }
    float* ps = (float*)myK;
    if (lq == 0) {
      #pragma unroll
      for (int c = 0; c < 8; ++c) ps[c * 16 + li] = pc[c];
    }
    LDS_FENCE();
    const short* F2NT = wsb + OFF_F2N;
    float yv[2];
    #pragma unroll
    for (int half = 0; half < 2; ++half) {
      int col = half * 64 + lane;
      float dot = 0.f;
      for (int d0 = 0; d0 < 128; d0 += 8) {
        bf16x8 wv8 = *(const bf16x8*)(F2NT + col * 128 + d0);
        f32x4 p0 = *(const f32x4*)(ps + d0);
        f32x4 p1 = *(const f32x4*)(ps + d0 + 4);
        dot += p0[0] * bf2f(wv8[0]) + p0[1] * bf2f(wv8[1]) + p0[2] * bf2f(wv8[2]) + p0[3] * bf2f(wv8[3]);
        dot += p1[0] * bf2f(wv8[4]) + p1[1] * bf2f(wv8[5]) + p1[2] * bf2f(wv8[6]) + p1[3] * bf2f(wv8[7]);
      }
      yv[half] = gelu_f(dot + f2n_b[col]) + node_h[(size_t)n * 128 + col];
    }
    float s1 = yv[0] + yv[1], s2 = yv[0] * yv[0] + yv[1] * yv[1];
    #pragma unroll
    for (int m = 1; m <= 32; m <<= 1) { s1 += __shfl_xor(s1, m, 64); s2 += __shfl_xor(s2, m, 64); }
    float mean = s1 * (1.f / 128.f);
    float var = s2 * (1.f / 128.f) - mean * mean;
    float rstd = rsqrtf(var + 1e-5f);
    #pragma unroll
    for (int half = 0; half < 2; ++half) {
      int col = half * 64 + lane;
      out[(size_t)n * 128 + col] = (yv[half] - mean) * rstd * fin_g[col] + fin_b[col];
    }
  } else {
    ST_TILE(myK, acc);   // hid dead; transpose f' through myK
    LDS_FENCE();
    #pragma unroll
    for (int j = 0; j < 4; ++j) {
      int row = lane >> 2, colb = (lane & 3) * 32 + j * 8;
      bf16x8 v = tile_ld8(myK, row, colb);
      *(bf16x8*)(fbuf + (size_t)n * 2048 + row * 128 + colb) = v;
    }
  }
}

extern "C" void kernel_launch(void* const* d_in, const int* in_sizes, int n_in,
                              void* d_out, int out_size, void* d_ws, size_t ws_size,
                              hipStream_t stream) {
  const float* node_h    = (const float*)d_in[0];
  const int*   src_idx   = (const int*)d_in[1];
  const float* edge_feat = (const float*)d_in[2];
  const float* t_arr     = (const float*)d_in[3];
  const float* t_now     = (const float*)d_in[4];
  const float* edge_fc_w = (const float*)d_in[5];
  const float* edge_fc_b = (const float*)d_in[6];
  const float* basis_frq = (const float*)d_in[7];
  const float* phase     = (const float*)d_in[8];
  const float* wq        = (const float*)d_in[9];
  const float* wk        = (const float*)d_in[10];
  const float* wv        = (const float*)d_in[11];
  const float* attn_fc_w = (const float*)d_in[12];
  const float* attn_fc_b = (const float*)d_in[13];
  const float* attn_ln_g = (const float*)d_in[14];
  const float* attn_ln_b = (const float*)d_in[15];
  const float* ffn_w1    = (const float*)d_in[16];
  const float* ffn_b1    = (const float*)d_in[17];
  const float* ffn_w2    = (const float*)d_in[18];
  const float* ffn_b2    = (const float*)d_in[19];
  const float* ffn_ln_g  = (const float*)d_in[20];
  const float* ffn_ln_b  = (const float*)d_in[21];
  const float* f2n_w     = (const float*)d_in[22];
  const float* f2n_b     = (const float*)d_in[23];
  const float* fin_g     = (const float*)d_in[24];
  const float* fin_b     = (const float*)d_in[25];
  short* wsb  = (short*)d_ws;
  short* fbuf = (short*)((char*)d_ws + FB_BYTE_OFF);

  prep_kernel<<<(TOTAL_W + 255) / 256, 256, 0, stream>>>(
      edge_fc_w, wq, wk, wv, attn_fc_w, ffn_w1, ffn_w2, f2n_w, wsb);
  attn_kernel<<<NN / 8, 512, 0, stream>>>(
      node_h, src_idx, edge_feat, t_arr, t_now, edge_fc_b, basis_frq, phase,
      attn_fc_b, attn_ln_g, attn_ln_b, wsb, fbuf, 0, 1);
  ffn_kernel<<<NN / 8, 512, 0, stream>>>(
      ffn_b1, ffn_b2, ffn_ln_g, ffn_ln_b, f2n_b, fin_g, fin_b, node_h,
      wsb, fbuf, (float*)d_out, 0, 0);
  attn_kernel<<<NN / 8, 512, 0, stream>>>(
      node_h, src_idx, edge_feat, t_arr, t_now, edge_fc_b, basis_frq, phase,
      attn_fc_b, attn_ln_g, attn_ln_b, wsb, fbuf, 1, 0);
  ffn_kernel<<<NN / 8, 512, 0, stream>>>(
      ffn_b1, ffn_b2, ffn_ln_g, ffn_ln_b, f2n_b, fin_g, fin_b, node_h,
      wsb, fbuf, (float*)d_out, 1, 1);
}

// Round 21
// 621.609 us; speedup vs baseline: 1.1122x; 1.0219x over previous
//
#include <hip/hip_runtime.h>

// Problem constants
#define NN 16384
// ws (bf16) region offsets, in elements
#define OFF_EWT 0
#define OFF_WQT 4096
#define OFF_WKT 36864
#define OFF_WVT 69632
#define OFF_AFT 102400
#define OFF_W1T 135168
#define OFF_W2T 266240
#define OFF_F2N 397312
#define TOTAL_W 413696
#define FB_BYTE_OFF (1 << 20)   // fbuf starts 1MB into d_ws; 16384 nodes x 4KB = 64MB

typedef __attribute__((ext_vector_type(8))) short bf16x8;
typedef __attribute__((ext_vector_type(4))) short bf16x4;
typedef __attribute__((ext_vector_type(4))) float f32x4;

// round-half-up bf16 conversion: 0.5-ulp max error (same bound as RNE), 1 VALU op cheaper
static __device__ __forceinline__ short f2bf(float f) {
  unsigned u = __builtin_bit_cast(unsigned, f);
  u += 0x8000u;
  return (short)(u >> 16);
}
static __device__ __forceinline__ float bf2f(short h) {
  unsigned u = ((unsigned)(unsigned short)h) << 16;
  return __builtin_bit_cast(float, u);
}
static __device__ __forceinline__ float gelu_f(float x) {
  float e = __expf(1.5957691216057308f * (x + 0.044715f * x * x * x));
  return x - x / (e + 1.0f);
}
static __device__ __forceinline__ f32x4 mfma16(bf16x8 a, bf16x8 b, f32x4 c) {
  return __builtin_amdgcn_mfma_f32_16x16x32_bf16(a, b, c, 0, 0, 0);
}
// XOR bank swizzle
#define SWZM(row) (((((row) & 7) << 4)) ^ ((((row) >> 3) & 3) << 5))
static __device__ __forceinline__ int swzb(int row, int col) {
  return row * 256 + ((col * 2) ^ SWZM(row));
}
static __device__ __forceinline__ bf16x8 tile_ld8(const short* base, int row, int col) {
  return *(const bf16x8*)((const char*)base + swzb(row, col));
}
static __device__ __forceinline__ void tile_st16(short* base, int row, int col, short v) {
  *(short*)((char*)base + swzb(row, col)) = v;
}
static __device__ __forceinline__ float tile_ldf(const short* base, int row, int col) {
  return bf2f(*(const short*)((const char*)base + swzb(row, col)));
}
static __device__ __forceinline__ void gll16(const short* sp, void* dstb) {
  __builtin_amdgcn_global_load_lds(
      (const __attribute__((address_space(1))) unsigned int*)sp,
      (__attribute__((address_space(3))) unsigned int*)dstb, 16, 0, 0);
}
// 16KB half stage for 8-wave WGs: 2 gll16 per wave (64 rows x 128)
static __device__ __forceinline__ void stage_h8(short* dst, const short* src, int stride,
                                                int w, int lane) {
  #pragma unroll
  for (int it = 0; it < 2; ++it) {
    int dbase = (it * 8 + w) * 1024;
    int d = dbase + lane * 16;
    int row = d >> 8;                        // 0..63
    int scolb = (d & 255) ^ SWZM(row);
    gll16(src + row * stride + (scolb >> 1), (char*)dst + dbase);
  }
}
// 32KB full-tile stage for 8-wave WGs (ffn): 4 gll16 per wave (128 rows x 128)
static __device__ __forceinline__ void stage_full8(short* dst, const short* src, int stride,
                                                   int w, int lane) {
  #pragma unroll
  for (int it = 0; it < 4; ++it) {
    int dbase = (it * 8 + w) * 1024;
    int d = dbase + lane * 16;
    int row = d >> 8;                        // 0..127
    int scolb = (d & 255) ^ SWZM(row);
    gll16(src + row * stride + (scolb >> 1), (char*)dst + dbase);
  }
}
// 4KB f-tile stage (16 rows x 128), per wave into its own tile
static __device__ __forceinline__ void stage_f(short* dst, const short* src, int lane) {
  #pragma unroll
  for (int it = 0; it < 4; ++it) {
    int dbase = it * 1024;
    int d = dbase + lane * 16;
    int row = d >> 8;                        // 0..15
    int scolb = (d & 255) ^ SWZM(row);
    gll16(src + row * 128 + (scolb >> 1), (char*)dst + dbase);
  }
}

#define LDS_FENCE() do {                                       \
    asm volatile("s_waitcnt lgkmcnt(0)" ::: "memory");         \
    __builtin_amdgcn_sched_barrier(0);                         \
  } while (0)

#define ENDSTEP() do {                                         \
    __syncthreads();                                           \
    short* _t = bc; bc = bn; bn = _t;                          \
  } while (0)

#define LD_FA(SRC)                                                        \
  _Pragma("unroll") for (int _s = 0; _s < 4; ++_s)                        \
      fA[_s] = tile_ld8((SRC), li, _s * 32 + lq * 8);

#define ST_TILE(T, ACC)                                                   \
  _Pragma("unroll") for (int _c = 0; _c < 8; ++_c)                        \
    _Pragma("unroll") for (int _r = 0; _r < 4; ++_r)                      \
      tile_st16((T), lq * 4 + _r, _c * 16 + li, f2bf((ACC)[_c][_r]));

// 64-row half projection with row offset: 16 B-frag reads feed 16 MFMAs
#define PROJ4H(BB, RO)                                                    \
    f32x4 g0 = F0, g1 = F0, g2 = F0, g3 = F0;                             \
    _Pragma("unroll") for (int _s = 0; _s < 4; ++_s) {                    \
      int _sc = _s * 32 + lq * 8;                                         \
      g0 = mfma16(fA[_s], tile_ld8((BB), (RO) + 0 + li, _sc), g0);        \
      g1 = mfma16(fA[_s], tile_ld8((BB), (RO) + 16 + li, _sc), g1);       \
      g2 = mfma16(fA[_s], tile_ld8((BB), (RO) + 32 + li, _sc), g2);       \
      g3 = mfma16(fA[_s], tile_ld8((BB), (RO) + 48 + li, _sc), g3);       \
    }

// store the 4 half-projection tiles into DST at col-block base HB*4
#define ST4H(DST, HB)                                                     \
    _Pragma("unroll") for (int _r = 0; _r < 4; ++_r) {                    \
      tile_st16((DST), lq * 4 + _r, ((HB) * 4 + 0) * 16 + li, f2bf(g0[_r])); \
      tile_st16((DST), lq * 4 + _r, ((HB) * 4 + 1) * 16 + li, f2bf(g1[_r])); \
      tile_st16((DST), lq * 4 + _r, ((HB) * 4 + 2) * 16 + li, f2bf(g2[_r])); \
      tile_st16((DST), lq * 4 + _r, ((HB) * 4 + 3) * 16 + li, f2bf(g3[_r])); \
    }

// half accumulate with row offset: acc[CB..CB+3] += A * staged rows RO..RO+63
#define ACC4H(AR, CB, BB, RO)                                             \
    _Pragma("unroll") for (int _s = 0; _s < 4; ++_s) {                    \
      int _sc = _s * 32 + lq * 8;                                         \
      acc[(CB) + 0] = mfma16(AR[_s], tile_ld8((BB), (RO) + 0 + li, _sc), acc[(CB) + 0]);  \
      acc[(CB) + 1] = mfma16(AR[_s], tile_ld8((BB), (RO) + 16 + li, _sc), acc[(CB) + 1]); \
      acc[(CB) + 2] = mfma16(AR[_s], tile_ld8((BB), (RO) + 32 + li, _sc), acc[(CB) + 2]); \
      acc[(CB) + 3] = mfma16(AR[_s], tile_ld8((BB), (RO) + 48 + li, _sc), acc[(CB) + 3]); \
    }

#define LAYER_NORM(A, GP, BP) do {                                        \
    float _gg[8], _bb[8];                                                 \
    _Pragma("unroll") for (int _c = 0; _c < 8; ++_c) {                    \
      _gg[_c] = (GP)[_c * 16 + li]; _bb[_c] = (BP)[_c * 16 + li]; }       \
    _Pragma("unroll") for (int _r = 0; _r < 4; ++_r) {                    \
      float _s1 = 0.f, _s2 = 0.f;                                         \
      _Pragma("unroll") for (int _c = 0; _c < 8; ++_c) {                  \
        float _v = (A)[_c][_r]; _s1 += _v; _s2 += _v * _v; }              \
      _Pragma("unroll") for (int _m = 1; _m <= 8; _m <<= 1) {             \
        _s1 += __shfl_xor(_s1, _m, 64); _s2 += __shfl_xor(_s2, _m, 64); } \
      float _mean = _s1 * (1.f / 128.f);                                  \
      float _var = _s2 * (1.f / 128.f) - _mean * _mean;                   \
      float _rstd = rsqrtf(_var + 1e-5f);                                 \
      _Pragma("unroll") for (int _c = 0; _c < 8; ++_c)                    \
        (A)[_c][_r] = ((A)[_c][_r] - _mean) * _rstd * _gg[_c] + _bb[_c];  \
    }                                                                     \
  } while (0)

// wave-private attention; overlays Vt->MYK, Os->MYQ (both dead)
#define ATTN(MYQ, MYK, VACC, OA) do {                                     \
    f32x4 _st[8];                                                         \
    _Pragma("unroll") for (int _h = 0; _h < 8; ++_h) {                    \
      bf16x8 _ka = B0, _qa = B0;                                          \
      if (lq < 2) {                                                       \
        _ka = tile_ld8((MYK), li, _h * 16 + lq * 8);                      \
        _qa = tile_ld8((MYQ), li, _h * 16 + lq * 8);                      \
      }                                                                   \
      _st[_h] = mfma16(_ka, _qa, F0);                                     \
    }                                                                     \
    LDS_FENCE();                                                          \
    _Pragma("unroll") for (int _c = 0; _c < 8; ++_c) {                    \
      bf16x4 _pk;                                                         \
      _Pragma("unroll") for (int _r = 0; _r < 4; ++_r)                    \
        _pk[_r] = f2bf((VACC)[_c][_r]);                                   \
      *(bf16x4*)((MYK) + (_c * 16 + li) * 16 + lq * 4) = _pk;             \
    }                                                                     \
    LDS_FENCE();                                                          \
    _Pragma("unroll") for (int _h = 0; _h < 8; ++_h) {                    \
      float _p[4]; float _mx = -1e30f;                                    \
      _Pragma("unroll") for (int _r = 0; _r < 4; ++_r) {                  \
        _p[_r] = _st[_h][_r] * 0.25f; _mx = fmaxf(_mx, _p[_r]); }         \
      _mx = fmaxf(_mx, __shfl_xor(_mx, 16, 64));                          \
      _mx = fmaxf(_mx, __shfl_xor(_mx, 32, 64));                          \
      float _sum = 0.f;                                                   \
      _Pragma("unroll") for (int _r = 0; _r < 4; ++_r) {                  \
        _p[_r] = __expf(_p[_r] - _mx); _sum += _p[_r]; }                  \
      _sum += __shfl_xor(_sum, 16, 64);                                   \
      _sum += __shfl_xor(_sum, 32, 64);                                   \
      float _inv = 1.0f / _sum;                                           \
      _Pragma("unroll") for (int _r = 0; _r < 4; ++_r) _p[_r] *= _inv;    \
      bf16x8 _pa;                                                         \
      _Pragma("unroll") for (int _j = 0; _j < 8; ++_j) {                  \
        float _v = __shfl(_p[_j & 3], li + 16 * (2 * lq + (_j >> 2)), 64);\
        _pa[_j] = (lq < 2) ? f2bf(_v) : (short)0;                         \
      }                                                                   \
      bf16x8 _vb = B0;                                                    \
      if (lq < 2) _vb = *(const bf16x8*)((MYK) + (_h * 16 + li) * 16 + lq * 8); \
      f32x4 _o = mfma16(_pa, _vb, F0);                                    \
      _Pragma("unroll") for (int _r = 0; _r < 4; ++_r)                    \
        tile_st16((MYQ), lq * 4 + _r, _h * 16 + li, f2bf(_o[_r]));        \
    }                                                                     \
    LDS_FENCE();                                                          \
    _Pragma("unroll") for (int _s = 0; _s < 4; ++_s)                      \
      (OA)[_s] = tile_ld8((MYQ), li, _s * 32 + lq * 8);                   \
  } while (0)

// ---- prep: transpose + fp32->bf16 all weight matrices into ws ----
__global__ void prep_kernel(const float* __restrict__ ew, const float* __restrict__ wq,
                            const float* __restrict__ wk, const float* __restrict__ wv,
                            const float* __restrict__ afc, const float* __restrict__ w1,
                            const float* __restrict__ w2, const float* __restrict__ f2n,
                            short* __restrict__ wsb) {
  int tt = blockIdx.x * 256 + threadIdx.x;
  if (tt >= TOTAL_W) return;
  short v;
  if (tt < OFF_WQT) {                       // EWT [128][32] <- ew [32][128]
    int u = tt; int row = u >> 5, colr = u & 31;
    v = f2bf(ew[colr * 128 + row]);
  } else if (tt < OFF_WKT) {                // WQT [2][128][128]
    int u = tt - OFF_WQT; int i = u >> 14; u &= 16383; int row = u >> 7, colr = u & 127;
    v = f2bf(wq[i * 16384 + colr * 128 + row]);
  } else if (tt < OFF_WVT) {
    int u = tt - OFF_WKT; int i = u >> 14; u &= 16383; int row = u >> 7, colr = u & 127;
    v = f2bf(wk[i * 16384 + colr * 128 + row]);
  } else if (tt < OFF_AFT) {
    int u = tt - OFF_WVT; int i = u >> 14; u &= 16383; int row = u >> 7, colr = u & 127;
    v = f2bf(wv[i * 16384 + colr * 128 + row]);
  } else if (tt < OFF_W1T) {                // AFT [2][128][128]
    int u = tt - OFF_AFT; int i = u >> 14; u &= 16383; int row = u >> 7, colr = u & 127;
    v = f2bf(afc[i * 16384 + colr * 128 + row]);
  } else if (tt < OFF_W2T) {                // W1T [2][512][128] <- w1 [2][128][512]
    int u = tt - OFF_W1T; int i = u >> 16; u &= 65535; int row = u >> 7, colr = u & 127;
    v = f2bf(w1[i * 65536 + colr * 512 + row]);
  } else if (tt < OFF_F2N) {                // W2T [2][128][512] <- w2 [2][512][128]
    int u = tt - OFF_W2T; int i = u >> 16; u &= 65535; int row = u >> 9, colr = u & 511;
    v = f2bf(w2[i * 65536 + colr * 128 + row]);
  } else {                                  // F2N [128][128] <- f2n [128][128]
    int u = tt - OFF_F2N; int row = u >> 7, colr = u & 127;
    v = f2bf(f2n[colr * 128 + row]);
  }
  wsb[tt] = v;
}

// ======== attention-half kernel: 16KB half-tile stages (10 steps) ========
__global__ __launch_bounds__(512, 2) void attn_kernel(
    const float* __restrict__ node_h, const int* __restrict__ src_idx,
    const float* __restrict__ edge_feat, const float* __restrict__ t_arr,
    const float* __restrict__ t_now, const float* __restrict__ edge_fc_b,
    const float* __restrict__ basis_freq, const float* __restrict__ phase,
    const float* __restrict__ attn_fc_b, const float* __restrict__ attn_ln_g,
    const float* __restrict__ attn_ln_b, const short* __restrict__ wsb,
    short* __restrict__ fbuf, int il, int do_msg) {
  __shared__ __align__(16) short bufs0[8192];   // 16KB half A
  __shared__ __align__(16) short bufs1[8192];   // 16KB half B
  __shared__ __align__(16) short qk[8][4096];   // per-wave Q(2048)+K(2048)

  const int tid = (int)threadIdx.x;
  const int w = tid >> 6, lane = tid & 63, li = lane & 15, lq = lane >> 4;
  const int n = (int)blockIdx.x * 8 + w;
  short* myQ = qk[w];
  short* myK = qk[w] + 2048;
  short* bc = bufs0;
  short* bn = bufs1;
  const f32x4 F0 = {0.f, 0.f, 0.f, 0.f};
  const bf16x8 B0 = {0, 0, 0, 0, 0, 0, 0, 0};
  const short* WQT = wsb + OFF_WQT + il * 16384;
  const short* WKT = wsb + OFF_WKT + il * 16384;
  const short* WVT = wsb + OFF_WVT + il * 16384;
  const short* AFT = wsb + OFF_AFT + il * 16384;

  stage_h8(bc, WQT, 128, w, lane);   // prologue: WQ h0 (rows 0..63)

  f32x4 acc[8];
  if (do_msg) {
    const float tnow = t_now[0];
    {
      const float* ef = edge_feat + ((size_t)(n * 16 + li)) * 32 + lq * 8;
      f32x4 e0 = *(const f32x4*)(ef);
      f32x4 e1 = *(const f32x4*)(ef + 4);
      bf16x8 ea;
      #pragma unroll
      for (int j = 0; j < 4; ++j) { ea[j] = f2bf(e0[j]); ea[j + 4] = f2bf(e1[j]); }
      const short* ewt = wsb + OFF_EWT;
      #pragma unroll
      for (int c = 0; c < 8; ++c) {
        bf16x8 eb = *(const bf16x8*)(ewt + (c * 16 + li) * 32 + lq * 8);
        acc[c] = mfma16(ea, eb, F0);
      }
    }
    {
      float bfq[8], phs[8], ebs[8];
      #pragma unroll
      for (int c = 0; c < 8; ++c) {
        int col = c * 16 + li;
        bfq[c] = basis_freq[col]; phs[c] = phase[col]; ebs[c] = edge_fc_b[col];
      }
      #pragma unroll
      for (int r = 0; r < 4; ++r) {
        int m = lq * 4 + r;
        int sidx = src_idx[n * 16 + m];
        float dt = tnow - t_arr[n * 16 + m];
        const float* nh = node_h + (size_t)sidx * 128;
        #pragma unroll
        for (int c = 0; c < 8; ++c) {
          int col = c * 16 + li;
          float x = gelu_f(acc[c][r] + ebs[c]);
          x += nh[col];
          x += __cosf(dt * bfq[c] + phs[c]);
          acc[c][r] = x;
        }
      }
    }
    ST_TILE(myQ, acc);
  } else {
    stage_f(myQ, fbuf + (size_t)n * 2048, lane);
  }
  __syncthreads();   // prologue stage + f tiles ready
  if (!do_msg) {
    #pragma unroll
    for (int c = 0; c < 8; ++c)
      #pragma unroll
      for (int r = 0; r < 4; ++r)
        acc[c][r] = tile_ldf(myQ, lq * 4 + r, c * 16 + li);
  }

  bf16x8 fA[4], oa_[4];

  // WQ halves
  #pragma unroll
  for (int h = 0; h < 2; ++h) {
    const short* nx = (h == 0) ? (WQT + 8192) : WKT;
    stage_h8(bn, nx, 128, w, lane);
    if (h == 0) LD_FA(myQ);
    { PROJ4H(bc, 0); ST4H(myQ, h); }
    ENDSTEP();
  }
  // WK halves
  #pragma unroll
  for (int h = 0; h < 2; ++h) {
    const short* nx = (h == 0) ? (WKT + 8192) : WVT;
    stage_h8(bn, nx, 128, w, lane);
    { PROJ4H(bc, 0); ST4H(myK, h); }
    ENDSTEP();
  }
  // WV halves (+ attention at h1)
  {
    f32x4 vacc[8];
    #pragma unroll
    for (int h = 0; h < 2; ++h) {
      const short* nx = (h == 0) ? (WVT + 8192) : AFT;
      stage_h8(bn, nx, 128, w, lane);
      {
        PROJ4H(bc, 0);
        vacc[h * 4 + 0] = g0; vacc[h * 4 + 1] = g1;
        vacc[h * 4 + 2] = g2; vacc[h * 4 + 3] = g3;
      }
      if (h == 1) {
        LDS_FENCE();
        ATTN(myQ, myK, vacc, oa_);
      }
      ENDSTEP();
    }
  }
  // AF halves
  #pragma unroll
  for (int h = 0; h < 2; ++h) {
    if (h == 0) stage_h8(bn, AFT + 8192, 128, w, lane);
    #pragma unroll
    for (int j = 0; j < 4; ++j) {
      float b = attn_fc_b[il * 128 + (h * 4 + j) * 16 + li];
      #pragma unroll
      for (int r = 0; r < 4; ++r) acc[h * 4 + j][r] += b;
    }
    ACC4H(oa_, h * 4, bc, 0);
    if (h == 1) {
      LAYER_NORM(acc, attn_ln_g + il * 128, attn_ln_b + il * 128);
      ST_TILE(myQ, acc);
    }
    ENDSTEP();
  }
  // epilogue: coalesced f' store
  LDS_FENCE();
  #pragma unroll
  for (int j = 0; j < 4; ++j) {
    int row = lane >> 2, colb = (lane & 3) * 32 + j * 8;
    bf16x8 v = tile_ld8(myQ, row, colb);
    *(bf16x8*)(fbuf + (size_t)n * 2048 + row * 128 + colb) = v;
  }
}

// ======== FFN-half kernel: 8 waves x 1 node, 32KB full-tile stages ========
__global__ __launch_bounds__(512, 2) void ffn_kernel(
    const float* __restrict__ ffn_b1, const float* __restrict__ ffn_b2,
    const float* __restrict__ ffn_ln_g, const float* __restrict__ ffn_ln_b,
    const float* __restrict__ f2n_b, const float* __restrict__ fin_g,
    const float* __restrict__ fin_b, const float* __restrict__ node_h,
    const short* __restrict__ wsb, short* __restrict__ fbuf,
    float* __restrict__ out, int il, int last) {
  __shared__ __align__(16) short bufs0[16384];  // 32KB full tile A
  __shared__ __align__(16) short bufs1[16384];  // 32KB full tile B
  __shared__ __align__(16) short qk[8][2048];   // per-wave f/hid tile

  const int tid = (int)threadIdx.x;
  const int w = tid >> 6, lane = tid & 63, li = lane & 15, lq = lane >> 4;
  const int n = (int)blockIdx.x * 8 + w;
  short* myK = qk[w];                 // f' tile at entry, then hid tile
  short* bc = bufs0;
  short* bn = bufs1;
  const f32x4 F0 = {0.f, 0.f, 0.f, 0.f};
  const short* W1T = wsb + OFF_W1T + il * 65536;
  const short* W2T = wsb + OFF_W2T + il * 65536;

  stage_full8(bc, W1T, 128, w, lane);   // prologue: W1 ct0 full tile
  stage_f(myK, fbuf + (size_t)n * 2048, lane);
  __syncthreads();

  bf16x8 fA[4], ha_[4];
  LD_FA(myK);
  f32x4 acc[8];
  #pragma unroll
  for (int c = 0; c < 8; ++c) {
    float b2 = ffn_b2[il * 128 + c * 16 + li];
    #pragma unroll
    for (int r = 0; r < 4; ++r)
      acc[c][r] = tile_ldf(myK, lq * 4 + r, c * 16 + li) + b2;
  }
  LDS_FENCE();   // f reads complete before hid overwrites myK

  for (int ct = 0; ct < 4; ++ct) {
    const short* W1c = W1T + ct * 16384;
    const short* W2c = W2T + ct * 128;
    const float* b1p = ffn_b1 + il * 512 + ct * 128;
    // step A: W1 full tile -> hid (two sub-phases, no barrier between)
    stage_full8(bn, W2c, 512, w, lane);
    #pragma unroll
    for (int h = 0; h < 2; ++h) {
      PROJ4H(bc, h * 64);
      #pragma unroll
      for (int j = 0; j < 4; ++j) {
        float b1 = b1p[(h * 4 + j) * 16 + li];
        f32x4 gx = j == 0 ? g0 : j == 1 ? g1 : j == 2 ? g2 : g3;
        #pragma unroll
        for (int r = 0; r < 4; ++r)
          tile_st16(myK, lq * 4 + r, (h * 4 + j) * 16 + li, f2bf(fmaxf(gx[r] + b1, 0.f)));
      }
    }
    LDS_FENCE();
    #pragma unroll
    for (int s = 0; s < 4; ++s) ha_[s] = tile_ld8(myK, li, s * 32 + lq * 8);
    ENDSTEP();
    // step B: W2 full tile -> acc (two sub-phases)
    if (ct < 3) stage_full8(bn, W1T + (ct + 1) * 16384, 128, w, lane);
    ACC4H(ha_, 0, bc, 0);
    ACC4H(ha_, 4, bc, 64);
    if (ct == 3)
      LAYER_NORM(acc, ffn_ln_g + il * 128, ffn_ln_b + il * 128);
    ENDSTEP();
  }

  if (last) {
    // pooling + fea2node + final LN  (myK dead, reuse as float scratch)
    float pc[8];
    #pragma unroll
    for (int c = 0; c < 8; ++c) {
      float s = acc[c][0] + acc[c][1] + acc[c][2] + acc[c][3];
      s += __shfl_xor(s, 16, 64);
      s += __shfl_xor(s, 32, 64);
      pc[c] = s * (1.f / 16.f);
    }
    float* ps = (float*)myK;
    if (lq == 0) {
      #pragma unroll
      for (int c = 0; c < 8; ++c) ps[c * 16 + li] = pc[c];
    }
    LDS_FENCE();
    const short* F2NT = wsb + OFF_F2N;
    float yv[2];
    #pragma unroll
    for (int half = 0; half < 2; ++half) {
      int col = half * 64 + lane;
      float dot = 0.f;
      for (int d0 = 0; d0 < 128; d0 += 8) {
        bf16x8 wv8 = *(const bf16x8*)(F2NT + col * 128 + d0);
        f32x4 p0 = *(const f32x4*)(ps + d0);
        f32x4 p1 = *(const f32x4*)(ps + d0 + 4);
        dot += p0[0] * bf2f(wv8[0]) + p0[1] * bf2f(wv8[1]) + p0[2] * bf2f(wv8[2]) + p0[3] * bf2f(wv8[3]);
        dot += p1[0] * bf2f(wv8[4]) + p1[1] * bf2f(wv8[5]) + p1[2] * bf2f(wv8[6]) + p1[3] * bf2f(wv8[7]);
      }
      yv[half] = gelu_f(dot + f2n_b[col]) + node_h[(size_t)n * 128 + col];
    }
    float s1 = yv[0] + yv[1], s2 = yv[0] * yv[0] + yv[1] * yv[1];
    #pragma unroll
    for (int m = 1; m <= 32; m <<= 1) { s1 += __shfl_xor(s1, m, 64); s2 += __shfl_xor(s2, m, 64); }
    float mean = s1 * (1.f / 128.f);
    float var = s2 * (1.f / 128.f) - mean * mean;
    float rstd = rsqrtf(var + 1e-5f);
    #pragma unroll
    for (int half = 0; half < 2; ++half) {
      int col = half * 64 + lane;
      out[(size_t)n * 128 + col] = (yv[half] - mean) * rstd * fin_g[col] + fin_b[col];
    }
  } else {
    ST_TILE(myK, acc);   // hid dead; transpose f' through myK
    LDS_FENCE();
    #pragma unroll
    for (int j = 0; j < 4; ++j) {
      int row = lane >> 2, colb = (lane & 3) * 32 + j * 8;
      bf16x8 v = tile_ld8(myK, row, colb);
      *(bf16x8*)(fbuf + (size_t)n * 2048 + row * 128 + colb) = v;
    }
  }
}

extern "C" void kernel_launch(void* const* d_in, const int* in_sizes, int n_in,
                              void* d_out, int out_size, void* d_ws, size_t ws_size,
                              hipStream_t stream) {
  const float* node_h    = (const float*)d_in[0];
  const int*   src_idx   = (const int*)d_in[1];
  const float* edge_feat = (const float*)d_in[2];
  const float* t_arr     = (const float*)d_in[3];
  const float* t_now     = (const float*)d_in[4];
  const float* edge_fc_w = (const float*)d_in[5];
  const float* edge_fc_b = (const float*)d_in[6];
  const float* basis_frq = (const float*)d_in[7];
  const float* phase     = (const float*)d_in[8];
  const float* wq        = (const float*)d_in[9];
  const float* wk        = (const float*)d_in[10];
  const float* wv        = (const float*)d_in[11];
  const float* attn_fc_w = (const float*)d_in[12];
  const float* attn_fc_b = (const float*)d_in[13];
  const float* attn_ln_g = (const float*)d_in[14];
  const float* attn_ln_b = (const float*)d_in[15];
  const float* ffn_w1    = (const float*)d_in[16];
  const float* ffn_b1    = (const float*)d_in[17];
  const float* ffn_w2    = (const float*)d_in[18];
  const float* ffn_b2    = (const float*)d_in[19];
  const float* ffn_ln_g  = (const float*)d_in[20];
  const float* ffn_ln_b  = (const float*)d_in[21];
  const float* f2n_w     = (const float*)d_in[22];
  const float* f2n_b     = (const float*)d_in[23];
  const float* fin_g     = (const float*)d_in[24];
  const float* fin_b     = (const float*)d_in[25];
  short* wsb  = (short*)d_ws;
  short* fbuf = (short*)((char*)d_ws + FB_BYTE_OFF);

  prep_kernel<<<(TOTAL_W + 255) / 256, 256, 0, stream>>>(
      edge_fc_w, wq, wk, wv, attn_fc_w, ffn_w1, ffn_w2, f2n_w, wsb);
  attn_kernel<<<NN / 8, 512, 0, stream>>>(
      node_h, src_idx, edge_feat, t_arr, t_now, edge_fc_b, basis_frq, phase,
      attn_fc_b, attn_ln_g, attn_ln_b, wsb, fbuf, 0, 1);
  ffn_kernel<<<NN / 8, 512, 0, stream>>>(
      ffn_b1, ffn_b2, ffn_ln_g, ffn_ln_b, f2n_b, fin_g, fin_b, node_h,
      wsb, fbuf, (float*)d_out, 0, 0);
  attn_kernel<<<NN / 8, 512, 0, stream>>>(
      node_h, src_idx, edge_feat, t_arr, t_now, edge_fc_b, basis_frq, phase,
      attn_fc_b, attn_ln_g, attn_ln_b, wsb, fbuf, 1, 0);
  ffn_kernel<<<NN / 8, 512, 0, stream>>>(
      ffn_b1, ffn_b2, ffn_ln_g, ffn_ln_b, f2n_b, fin_g, fin_b, node_h,
      wsb, fbuf, (float*)d_out, 1, 1);
}